// Round 4
// baseline (821.603 us; speedup 1.0000x reference)
//
#include <hip/hip_runtime.h>

// RWKV-5 WKV via chunked linear attention + MFMA (bf16 operands, f32 accum).
// B=4, T=4096, H=32, S=64. State scaled: X = s_raw*SCALE.
// Subchunk L=64:  out = strictTril(rw@kw^T + diag)@v' + rw@X0
//                 X_L = td^L * X0 + kw2^T@v'
//   rw_i[s]=r_i[s]*td^i, kw_j[s]=k_j[s]*td^-(j+1), kw2_j[s]=k_j[s]*td^(63-j)
// pass0: power tables pw[i]=td^i, ipw[i]=td^-i (i=0..64), per head.
// pass1: per-(bh, superchunk of 1024) from-zero end state (4 waves, reg-only).
// pass2: propagate superchunk entry states.
// pass3: full compute; waves0-3: A-GEMM -> LDS -> out-GEMM; waves4-7: W-GEMM
//        + X chain in regs, X published as swizzled bf16 LDS ping-pong.

namespace {
constexpr int cB = 4, cT = 4096, cH = 32, cS = 64;
constexpr int cTS = cH * cS;             // 2048
constexpr float cScale = 1.0f / 128.0f;
constexpr int cSC = 4;                   // superchunks
constexpr int cSCL = cT / cSC;           // 1024
constexpr int cL = 64;                   // subchunk length
constexpr int cNS = cSCL / cL;           // 16 subchunks per block
constexpr int cBH = cB * cH;             // 128
constexpr int wsXoff = 524288;           // float offset of X buffer (2MB)
}

typedef __bf16 bf16x8 __attribute__((ext_vector_type(8)));
typedef float  f32x16 __attribute__((ext_vector_type(16)));
typedef unsigned short us8 __attribute__((ext_vector_type(8)));

__device__ __forceinline__ int swz8(int row, int col) {
    return (row * 64 + col) ^ ((row & 7) << 3);   // u16 units, XOR 16B slots
}
__device__ __forceinline__ unsigned short bfb(float x) {
    __bf16 h = (__bf16)x;
    return __builtin_bit_cast(unsigned short, h);
}

// ---------------- pass0: decay power tables --------------------------------
__global__ __launch_bounds__(64)
void rwkv5_tables(const float* __restrict__ TD, float* __restrict__ pwt) {
    const int h = blockIdx.x, s = threadIdx.x;
    const float t = TD[h * cS + s];
    float* base = pwt + (size_t)h * 130 * cS + s;
    float p = 1.0f;
    for (int i = 0; i <= cL; ++i) { base[(size_t)i * cS] = p; p *= t; }
    const float it = 1.0f / t;
    p = 1.0f;
    for (int i = 0; i <= cL; ++i) { base[(size_t)(65 + i) * cS] = p; p *= it; }
}

// ---------------- pass1: from-zero superchunk end states -------------------
__global__ __launch_bounds__(256)
void rwkv5_pass1(const float* __restrict__ K, const float* __restrict__ V,
                 const float* __restrict__ pwt, float* __restrict__ Xb) {
    const int u = blockIdx.x, bh = u >> 2, sc = u & 3;
    const int b = bh >> 5, h = bh & 31;
    const int tid = threadIdx.x, q = tid >> 6, l = tid & 63;
    const int lo = l & 31, hi = l >> 5;
    const int dh = q >> 1, sh = q & 1;
    const int dA = lo + 32 * dh, s = lo + 32 * sh;
    const float* pwh = pwt + (size_t)h * 130 * cS;
    const size_t tbase = ((size_t)b * cT + (size_t)sc * cSCL) * cTS + h * cS;
    const float* kb = K + tbase;
    const float* vb = V + tbase;
    const float tdL = pwh[64 * cS + s];

    f32x16 x;
#pragma unroll
    for (int i = 0; i < 16; ++i) x[i] = 0.0f;

    for (int c = 0; c < cNS; ++c) {
        const int t0 = c * cL;
        bf16x8 av[4], bw[4];
#pragma unroll
        for (int ks = 0; ks < 4; ++ks) {
#pragma unroll
            for (int e = 0; e < 8; ++e) {
                const int j = ks * 16 + hi * 8 + e;
                av[ks][e] = (__bf16)(vb[(t0 + j) * cTS + dA] * cScale);
                bw[ks][e] = (__bf16)(kb[(t0 + j) * cTS + s] *
                                     pwh[(63 - j) * cS + s]);
            }
        }
        f32x16 w;
#pragma unroll
        for (int i = 0; i < 16; ++i) w[i] = 0.0f;
#pragma unroll
        for (int ks = 0; ks < 4; ++ks)
            w = __builtin_amdgcn_mfma_f32_32x32x16_bf16(av[ks], bw[ks], w,
                                                        0, 0, 0);
#pragma unroll
        for (int i = 0; i < 16; ++i) x[i] = tdL * x[i] + w[i];
    }
    float* xp = Xb + (size_t)u * cS * cS;
#pragma unroll
    for (int r = 0; r < 16; ++r) {
        const int dr = (r & 3) + 8 * (r >> 2) + 4 * hi + 32 * dh;
        xp[(size_t)s * cS + dr] = x[r];
    }
}

// ---------------- pass2: propagate superchunk entry states -----------------
__global__ __launch_bounds__(256)
void rwkv5_pass2(const float* __restrict__ S2in, const float* __restrict__ pwt,
                 float* __restrict__ Xb) {
    const int bh = blockIdx.x, h = bh & 31;
    const int t = threadIdx.x, s = t >> 2, db = (t & 3) * 16;
    float dL = pwt[(size_t)h * 130 * cS + 64 * cS + s];   // td^64
    dL *= dL; dL *= dL; dL *= dL; dL *= dL;               // td^1024

    float4 x[4];
    const float* s0 = S2in + ((size_t)bh * cS + s) * cS + db;
#pragma unroll
    for (int i = 0; i < 4; ++i) {
        x[i] = *(const float4*)(s0 + i * 4);
        x[i].x *= cScale; x[i].y *= cScale; x[i].z *= cScale; x[i].w *= cScale;
    }
    for (int sc = 0; sc < cSC; ++sc) {
        float* base = Xb + ((size_t)(bh * cSC + sc) * cS + s) * cS + db;
        float4 pr[4];
#pragma unroll
        for (int i = 0; i < 4; ++i) pr[i] = *(const float4*)(base + i * 4);
#pragma unroll
        for (int i = 0; i < 4; ++i) *(float4*)(base + i * 4) = x[i];
#pragma unroll
        for (int i = 0; i < 4; ++i) {
            x[i].x = fmaf(dL, x[i].x, pr[i].x);
            x[i].y = fmaf(dL, x[i].y, pr[i].y);
            x[i].z = fmaf(dL, x[i].z, pr[i].z);
            x[i].w = fmaf(dL, x[i].w, pr[i].w);
        }
    }
}

// ---------------- pass3: main compute --------------------------------------
__global__ __launch_bounds__(512, 4)
void rwkv5_pass3(const float* __restrict__ K, const float* __restrict__ V,
                 const float* __restrict__ R, const float* __restrict__ TF,
                 const float* __restrict__ pwt, const float* __restrict__ Xb,
                 float* __restrict__ Out) {
    __shared__ alignas(16) unsigned short Ash[64 * 64];
    __shared__ alignas(16) unsigned short Xsh[2][64 * 64];
    const int u = blockIdx.x, bh = u >> 2, sc = u & 3;
    const int b = bh >> 5, h = bh & 31;
    const int tid = threadIdx.x, wid = tid >> 6, l = tid & 63;
    const int lo = l & 31, hi = l >> 5;
    const float* pwh = pwt + (size_t)h * 130 * cS;
    const size_t tbase = ((size_t)b * cT + (size_t)sc * cSCL) * cTS + h * cS;
    const float* kb = K + tbase;
    const float* vb = V + tbase;
    const float* rb = R + tbase;
    float* ob = Out + tbase;

    if (wid < 4) {
        // -------- GEMM waves: A then out --------
        const int q = wid;
        const int ih = (q == 1 || q == 2) ? 1 : 0;   // row tile (rw / A / out)
        const int jh = (q == 2) ? 1 : 0;             // A col tile
        const int dh = (q >= 2) ? 1 : 0;             // out col tile
        const int iA = lo + 32 * ih;
        const int jB = lo + 32 * jh;
        const int dC = lo + 32 * dh;
        const bool doG1 = (q < 3);
        const bool doDiag = (q == 0 || q == 2);
        const int nksA = ih ? 4 : 2;                 // causal skip for i<32

        for (int c = 0; c < cNS; ++c) {
            const int t0 = c * cL;
            // rw fragments: row iA, k-dim s
            bf16x8 rwf[4];
#pragma unroll
            for (int ks = 0; ks < 4; ++ks) {
                const int sb = ks * 16 + hi * 8;
                const float4 r0 = *(const float4*)&rb[(t0 + iA) * cTS + sb];
                const float4 r1 = *(const float4*)&rb[(t0 + iA) * cTS + sb + 4];
                const float4 p0 = *(const float4*)&pwh[iA * cS + sb];
                const float4 p1 = *(const float4*)&pwh[iA * cS + sb + 4];
                rwf[ks][0] = (__bf16)(r0.x * p0.x);
                rwf[ks][1] = (__bf16)(r0.y * p0.y);
                rwf[ks][2] = (__bf16)(r0.z * p0.z);
                rwf[ks][3] = (__bf16)(r0.w * p0.w);
                rwf[ks][4] = (__bf16)(r1.x * p1.x);
                rwf[ks][5] = (__bf16)(r1.y * p1.y);
                rwf[ks][6] = (__bf16)(r1.z * p1.z);
                rwf[ks][7] = (__bf16)(r1.w * p1.w);
            }
            if (doG1) {
                bf16x8 kwf[4];
#pragma unroll
                for (int ks = 0; ks < 4; ++ks) {
                    const int sb = ks * 16 + hi * 8;
                    const float4 k0 = *(const float4*)&kb[(t0 + jB) * cTS + sb];
                    const float4 k1 = *(const float4*)&kb[(t0 + jB) * cTS + sb + 4];
                    const float4 q0 = *(const float4*)&pwh[(66 + jB) * cS + sb];
                    const float4 q1 = *(const float4*)&pwh[(66 + jB) * cS + sb + 4];
                    kwf[ks][0] = (__bf16)(k0.x * q0.x);
                    kwf[ks][1] = (__bf16)(k0.y * q0.y);
                    kwf[ks][2] = (__bf16)(k0.z * q0.z);
                    kwf[ks][3] = (__bf16)(k0.w * q0.w);
                    kwf[ks][4] = (__bf16)(k1.x * q1.x);
                    kwf[ks][5] = (__bf16)(k1.y * q1.y);
                    kwf[ks][6] = (__bf16)(k1.z * q1.z);
                    kwf[ks][7] = (__bf16)(k1.w * q1.w);
                }
                f32x16 acc1;
#pragma unroll
                for (int i = 0; i < 16; ++i) acc1[i] = 0.0f;
#pragma unroll
                for (int ks = 0; ks < 4; ++ks)
                    acc1 = __builtin_amdgcn_mfma_f32_32x32x16_bf16(
                        rwf[ks], kwf[ks], acc1, 0, 0, 0);
                float diagv = 0.0f;
                if (doDiag) {
                    float ds_ = 0.0f;
                    const int iD = jB;   // diag index == this lane's column
#pragma unroll
                    for (int m = 0; m < 8; ++m) {
                        const int sb = hi * 32 + m * 4;
                        const float4 rr = *(const float4*)&rb[(t0 + iD) * cTS + sb];
                        const float4 kk = *(const float4*)&kb[(t0 + iD) * cTS + sb];
                        const float4 tf = *(const float4*)&TF[h * cS + sb];
                        ds_ += rr.x * tf.x * kk.x + rr.y * tf.y * kk.y +
                               rr.z * tf.z * kk.z + rr.w * tf.w * kk.w;
                    }
                    diagv = ds_ + __shfl_xor(ds_, 32, 64);
                }
                // mask to strict lower triangle + diag, store bf16 A
#pragma unroll
                for (int r = 0; r < 16; ++r) {
                    const int row = (r & 3) + 8 * (r >> 2) + 4 * hi + 32 * ih;
                    const float v_ = (jB < row) ? acc1[r]
                                   : ((jB == row) ? diagv : 0.0f);
                    Ash[swz8(row, jB)] = bfb(v_);
                }
            }
            __syncthreads();   // A + X_c ready
            f32x16 acc3;
#pragma unroll
            for (int i = 0; i < 16; ++i) acc3[i] = 0.0f;
            // out = A @ v'
#pragma unroll
            for (int ks = 0; ks < 4; ++ks) {
                if (ks < nksA) {
                    bf16x8 vf;
#pragma unroll
                    for (int e = 0; e < 8; ++e) {
                        const int j = ks * 16 + hi * 8 + e;
                        vf[e] = (__bf16)(vb[(t0 + j) * cTS + dC] * cScale);
                    }
                    const us8 a_ = *(const us8*)&Ash[swz8(iA, ks * 16 + hi * 8)];
                    acc3 = __builtin_amdgcn_mfma_f32_32x32x16_bf16(
                        __builtin_bit_cast(bf16x8, a_), vf, acc3, 0, 0, 0);
                }
            }
            // out += rw @ X_c
#pragma unroll
            for (int ks = 0; ks < 4; ++ks) {
                const us8 x_ =
                    *(const us8*)&Xsh[c & 1][swz8(dC, ks * 16 + hi * 8)];
                acc3 = __builtin_amdgcn_mfma_f32_32x32x16_bf16(
                    rwf[ks], __builtin_bit_cast(bf16x8, x_), acc3, 0, 0, 0);
            }
#pragma unroll
            for (int r = 0; r < 16; ++r) {
                const int row = (r & 3) + 8 * (r >> 2) + 4 * hi + 32 * ih;
                ob[(t0 + row) * cTS + dC] = acc3[r];
            }
            __syncthreads();   // readers done; next iter may overwrite
        }
    } else {
        // -------- state waves: W-GEMM + X chain --------
        const int q = wid - 4, dh = q >> 1, sh = q & 1;
        const int dA = lo + 32 * dh, s = lo + 32 * sh;
        const float tdL = pwh[64 * cS + s];
        f32x16 x;
        const float* xin = Xb + (size_t)u * cS * cS;
#pragma unroll
        for (int r = 0; r < 16; ++r) {
            const int dr = (r & 3) + 8 * (r >> 2) + 4 * hi + 32 * dh;
            x[r] = xin[(size_t)s * cS + dr];
            Xsh[0][swz8(dr, s)] = bfb(x[r]);
        }
        for (int c = 0; c < cNS; ++c) {
            const int t0 = c * cL;
            bf16x8 av[4], bw[4];
#pragma unroll
            for (int ks = 0; ks < 4; ++ks) {
#pragma unroll
                for (int e = 0; e < 8; ++e) {
                    const int j = ks * 16 + hi * 8 + e;
                    av[ks][e] = (__bf16)(vb[(t0 + j) * cTS + dA] * cScale);
                    bw[ks][e] = (__bf16)(kb[(t0 + j) * cTS + s] *
                                         pwh[(63 - j) * cS + s]);
                }
            }
            f32x16 w;
#pragma unroll
            for (int i = 0; i < 16; ++i) w[i] = 0.0f;
#pragma unroll
            for (int ks = 0; ks < 4; ++ks)
                w = __builtin_amdgcn_mfma_f32_32x32x16_bf16(av[ks], bw[ks], w,
                                                            0, 0, 0);
#pragma unroll
            for (int i = 0; i < 16; ++i) x[i] = tdL * x[i] + w[i];
            const int nb = (c + 1) & 1;
#pragma unroll
            for (int r = 0; r < 16; ++r) {
                const int dr = (r & 3) + 8 * (r >> 2) + 4 * hi + 32 * dh;
                Xsh[nb][swz8(dr, s)] = bfb(x[r]);
            }
            __syncthreads();
            __syncthreads();
        }
        if (sc == cSC - 1) {
            float* o2 = Out + (size_t)cB * cT * cTS + (size_t)bh * cS * cS;
#pragma unroll
            for (int r = 0; r < 16; ++r) {
                const int dr = (r & 3) + 8 * (r >> 2) + 4 * hi + 32 * dh;
                o2[(size_t)s * cS + dr] = x[r] * 128.0f;
            }
        }
    }
}

extern "C" void kernel_launch(void* const* d_in, const int* in_sizes, int n_in,
                              void* d_out, int out_size, void* d_ws,
                              size_t ws_size, hipStream_t stream) {
    const float* K    = (const float*)d_in[0];
    const float* V    = (const float*)d_in[1];
    const float* R    = (const float*)d_in[2];
    const float* S2in = (const float*)d_in[3];
    const float* TF   = (const float*)d_in[4];
    const float* TD   = (const float*)d_in[5];
    float* OutP = (float*)d_out;
    float* pwt = (float*)d_ws;            // [32][130][64] f32 ~1.1 MB
    float* Xb  = (float*)d_ws + wsXoff;   // [512][64][64] f32 = 8 MB
    (void)in_sizes; (void)n_in; (void)ws_size; (void)out_size;

    rwkv5_tables<<<dim3(cH), dim3(64), 0, stream>>>(TD, pwt);
    rwkv5_pass1<<<dim3(cBH * cSC), dim3(256), 0, stream>>>(K, V, pwt, Xb);
    rwkv5_pass2<<<dim3(cBH), dim3(256), 0, stream>>>(S2in, pwt, Xb);
    rwkv5_pass3<<<dim3(cBH * cSC), dim3(512), 0, stream>>>(K, V, R, TF, pwt,
                                                           Xb, OutP);
}

// Round 5
// 445.694 us; speedup vs baseline: 1.8434x; 1.8434x over previous
//
#include <hip/hip_runtime.h>

// RWKV-5 WKV via chunked linear attention + MFMA, LDS-staged bf16 tiles.
// B=4, T=4096, H=32, S=64. State scaled: X = s_raw*SCALE (X' = td*X + k (x) v').
// Subchunk L=64: out = [strictTril(RW@KW^T) + diag]@VS + RW@X0 ;
//                X_L = td^64*X0 + KW2^T@VS
//   RW[i][s]=r_i[s]*td^i, KW[j][s]=k_j[s]*td^-(j+1), KW2[j][s]=k_j[s]*td^(63-j)
//   diag_i = sum_s r_i tf k_i  (computed f32 during staging)
// pass0: per-head power tables. pass1: from-zero superchunk partials (sc 0..2).
// pass2: propagate entry states (in-place in Buf). pass3: main compute.
// Tiles reg-staged coalesced -> pre-scaled bf16 -> XOR-swizzled LDS; raw
// s_barrier + lgkmcnt keeps global prefetch in flight across barriers.

namespace {
constexpr int cB = 4, cT = 4096, cH = 32, cS = 64;
constexpr int cTS = cH * cS;                 // 2048
constexpr float cScale = 1.0f / 128.0f;
constexpr int cSC = 4, cSCL = cT / cSC;      // 4 superchunks of 1024
constexpr int cL = 64, cNS = cSCL / cL;      // 16 subchunks of 64
constexpr int cBH = cB * cH;                 // 128
constexpr size_t wsBuf = 266240;             // float offset after pw tables
}

typedef __bf16 bf16x8 __attribute__((ext_vector_type(8)));
typedef float  f32x16 __attribute__((ext_vector_type(16)));
typedef unsigned short u16x4 __attribute__((ext_vector_type(4)));
typedef unsigned short u16x8 __attribute__((ext_vector_type(8)));

#define BARRIER() asm volatile("s_waitcnt lgkmcnt(0)\n\ts_barrier" ::: "memory")

__device__ __forceinline__ int swzb(int row, int byteInRow) {
    return row * 128 + (byteInRow ^ ((row & 15) << 3));   // bf16 tile, 128B rows
}
__device__ __forceinline__ int crow(int r, int hi) {
    return (r & 3) + 8 * (r >> 2) + 4 * hi;               // 32x32 C-layout row
}
__device__ __forceinline__ unsigned short bfb(float x) {
    return __builtin_bit_cast(unsigned short, (__bf16)x);
}
__device__ __forceinline__ bf16x8 ldRowFrag(const unsigned short* T, int row, int col) {
    const char* p = (const char*)T;
    u16x4 a = *(const u16x4*)(p + swzb(row, col * 2));
    u16x4 b = *(const u16x4*)(p + swzb(row, col * 2 + 8));
    u16x8 r = {a[0], a[1], a[2], a[3], b[0], b[1], b[2], b[3]};
    return __builtin_bit_cast(bf16x8, r);
}
__device__ __forceinline__ bf16x8 ldColFrag(const unsigned short* T, int row0, int col) {
    const char* p = (const char*)T;
    u16x8 r;
#pragma unroll
    for (int e = 0; e < 8; ++e)
        r[e] = *(const unsigned short*)(p + swzb(row0 + e, col * 2));
    return __builtin_bit_cast(bf16x8, r);
}
__device__ __forceinline__ void stRow8(unsigned short* T, int row, int col, u16x8 v) {
    char* p = (char*)T;
    u16x4 a = {v[0], v[1], v[2], v[3]}, b = {v[4], v[5], v[6], v[7]};
    *(u16x4*)(p + swzb(row, col * 2)) = a;
    *(u16x4*)(p + swzb(row, col * 2 + 8)) = b;
}
__device__ __forceinline__ void stEl(unsigned short* T, int row, int col, float x) {
    *(unsigned short*)((char*)T + swzb(row, col * 2)) = bfb(x);
}

// ---------------- pass0: decay power tables ---------------------------------
__global__ __launch_bounds__(64)
void rwkv5_tables(const float* __restrict__ TD, float* __restrict__ pwt) {
    const int h = blockIdx.x, s = threadIdx.x;
    const float t = TD[h * cS + s];
    float* base = pwt + (size_t)h * 130 * cS + s;
    float p = 1.0f;
    for (int i = 0; i <= cL; ++i) { base[(size_t)i * cS] = p; p *= t; }
    const float it = 1.0f / t;
    p = 1.0f;
    for (int i = 0; i <= cL; ++i) { base[(size_t)(65 + i) * cS] = p; p *= it; }
}

// ---------------- pass1: from-zero superchunk partials (sc 0..2) ------------
__global__ __launch_bounds__(256)
void rwkv5_pass1(const float* __restrict__ K, const float* __restrict__ V,
                 const float* __restrict__ pwt, float* __restrict__ Buf) {
    __shared__ alignas(16) unsigned short KW2s[4096], VSs[4096];
    const int bh = blockIdx.x, sc = blockIdx.y;
    const int b = bh >> 5, h = bh & 31;
    const int tid = threadIdx.x, wid = tid >> 6, l = tid & 63;
    const int lo = l & 31, hi = l >> 5;
    const int dhs = wid >> 1, shs = wid & 1;
    const int dS = lo + 32 * dhs, sS = lo + 32 * shs;
    const float* pwh = pwt + (size_t)h * 130 * cS;
    const size_t tbase = ((size_t)b * cT + (size_t)sc * cSCL) * cTS + h * cS;
    const float* kb = K + tbase;
    const float* vb = V + tbase;

    const int st = tid >> 2, c16 = (tid & 3) * 16;
    float pwC[16];
#pragma unroll
    for (int e = 0; e < 16; ++e) pwC[e] = pwh[(63 - st) * cS + c16 + e];

    float kx[16], vx[16];
    auto gload = [&](int cc) {
        const int c_ = (cc < cNS) ? cc : cNS - 1;
        const size_t off = ((size_t)(c_ * cL + st)) * cTS + c16;
#pragma unroll
        for (int i = 0; i < 4; ++i) {
            *(float4*)&kx[i * 4] = *(const float4*)(kb + off + i * 4);
            *(float4*)&vx[i * 4] = *(const float4*)(vb + off + i * 4);
        }
    };
    auto tileWrite = [&]() {
        u16x8 w;
#pragma unroll
        for (int half = 0; half < 2; ++half) {
#pragma unroll
            for (int e = 0; e < 8; ++e) w[e] = bfb(kx[half * 8 + e] * pwC[half * 8 + e]);
            stRow8(KW2s, st, c16 + half * 8, w);
#pragma unroll
            for (int e = 0; e < 8; ++e) w[e] = bfb(vx[half * 8 + e] * cScale);
            stRow8(VSs, st, c16 + half * 8, w);
        }
    };

    const float tdL = pwh[64 * cS + sS];
    f32x16 x;
#pragma unroll
    for (int i = 0; i < 16; ++i) x[i] = 0.f;

    gload(0); tileWrite(); gload(1);
    BARRIER();
    for (int c = 0; c < cNS; ++c) {
        f32x16 w;
#pragma unroll
        for (int i = 0; i < 16; ++i) w[i] = 0.f;
#pragma unroll
        for (int ks = 0; ks < 4; ++ks) {
            bf16x8 vaf = ldColFrag(VSs, ks * 16 + hi * 8, dS);
            bf16x8 k2f = ldColFrag(KW2s, ks * 16 + hi * 8, sS);
            w = __builtin_amdgcn_mfma_f32_32x32x16_bf16(vaf, k2f, w, 0, 0, 0);
        }
#pragma unroll
        for (int i = 0; i < 16; ++i) x[i] = tdL * x[i] + w[i];
        BARRIER();
        if (c + 1 < cNS) tileWrite();
        if (c < cNS - 2) gload(c + 2);
        BARRIER();
    }
    float* xp = Buf + ((size_t)bh * cSC + sc) * cS * cS;
#pragma unroll
    for (int r = 0; r < 16; ++r)
        xp[(size_t)sS * cS + crow(r, hi) + 32 * dhs] = x[r];
}

// ---------------- pass2: propagate entry states (in place) ------------------
__global__ __launch_bounds__(256)
void rwkv5_pass2(const float* __restrict__ S2in, const float* __restrict__ pwt,
                 float* __restrict__ Buf) {
    const int bh = blockIdx.x, h = bh & 31;
    const int t = threadIdx.x, s = t >> 2, db = (t & 3) * 16;
    float d = pwt[(size_t)h * 130 * cS + 64 * cS + s];   // td^64
    d *= d; d *= d; d *= d; d *= d;                      // td^1024
    float4 x[4];
    const float* s0 = S2in + ((size_t)bh * cS + s) * cS + db;
#pragma unroll
    for (int i = 0; i < 4; ++i) {
        x[i] = *(const float4*)(s0 + i * 4);
        x[i].x *= cScale; x[i].y *= cScale; x[i].z *= cScale; x[i].w *= cScale;
    }
    for (int sc = 0; sc < cSC; ++sc) {
        float* base = Buf + (((size_t)bh * cSC + sc) * cS + s) * cS + db;
        float4 pr[4];
        if (sc < cSC - 1) {
#pragma unroll
            for (int i = 0; i < 4; ++i) pr[i] = *(const float4*)(base + i * 4);
        }
#pragma unroll
        for (int i = 0; i < 4; ++i) *(float4*)(base + i * 4) = x[i];
        if (sc < cSC - 1) {
#pragma unroll
            for (int i = 0; i < 4; ++i) {
                x[i].x = fmaf(d, x[i].x, pr[i].x);
                x[i].y = fmaf(d, x[i].y, pr[i].y);
                x[i].z = fmaf(d, x[i].z, pr[i].z);
                x[i].w = fmaf(d, x[i].w, pr[i].w);
            }
        }
    }
}

// ---------------- pass3: main compute ----------------------------------------
__global__ __launch_bounds__(512)
void rwkv5_pass3(const float* __restrict__ K, const float* __restrict__ V,
                 const float* __restrict__ R, const float* __restrict__ TF,
                 const float* __restrict__ pwt, const float* __restrict__ Buf,
                 float* __restrict__ Out) {
    __shared__ alignas(16) unsigned short RWs[4096], KWs[4096], KW2s[4096],
                                          VSs[4096], As[4096], XTs[2][4096];
    __shared__ float DIAGs[64];
    const int u = blockIdx.x, bh = u >> 2, sc = u & 3;
    const int b = bh >> 5, h = bh & 31;
    const int tid = threadIdx.x, wid = tid >> 6, l = tid & 63;
    const int lo = l & 31, hi = l >> 5;
    const float* pwh = pwt + (size_t)h * 130 * cS;
    const size_t tbase = ((size_t)b * cT + (size_t)sc * cSCL) * cTS + h * cS;
    const float *kb = K + tbase, *vb = V + tbase, *rb = R + tbase;
    float* ob = Out + tbase;

    // staging role: thread -> tile row st, 8 cols at sc8
    const int st = tid >> 3, sc8 = (tid & 7) * 8;
    float pwA[8], ipwB[8], pwC[8], tfv[8];
#pragma unroll
    for (int e = 0; e < 8; ++e) {
        pwA[e]  = pwh[st * cS + sc8 + e];          // td^st
        ipwB[e] = pwh[(66 + st) * cS + sc8 + e];   // td^-(st+1)
        pwC[e]  = pwh[(63 - st) * cS + sc8 + e];   // td^(63-st)
        tfv[e]  = TF[h * cS + sc8 + e];
    }
    float kx[8], vx[8], rx[8];
    auto gload = [&](int cc) {
        const int c_ = (cc < cNS) ? cc : cNS - 1;
        const size_t off = ((size_t)(c_ * cL + st)) * cTS + sc8;
        *(float4*)&kx[0] = *(const float4*)(kb + off);
        *(float4*)&kx[4] = *(const float4*)(kb + off + 4);
        *(float4*)&vx[0] = *(const float4*)(vb + off);
        *(float4*)&vx[4] = *(const float4*)(vb + off + 4);
        *(float4*)&rx[0] = *(const float4*)(rb + off);
        *(float4*)&rx[4] = *(const float4*)(rb + off + 4);
    };
    auto tileWrite = [&]() {
        u16x8 w;
#pragma unroll
        for (int e = 0; e < 8; ++e) w[e] = bfb(rx[e] * pwA[e]);
        stRow8(RWs, st, sc8, w);
#pragma unroll
        for (int e = 0; e < 8; ++e) w[e] = bfb(kx[e] * ipwB[e]);
        stRow8(KWs, st, sc8, w);
#pragma unroll
        for (int e = 0; e < 8; ++e) w[e] = bfb(kx[e] * pwC[e]);
        stRow8(KW2s, st, sc8, w);
#pragma unroll
        for (int e = 0; e < 8; ++e) w[e] = bfb(vx[e] * cScale);
        stRow8(VSs, st, sc8, w);
        float p = 0.f;
#pragma unroll
        for (int e = 0; e < 8; ++e) p = fmaf(rx[e] * tfv[e], kx[e], p);
        p += __shfl_xor(p, 1, 64);
        p += __shfl_xor(p, 2, 64);
        p += __shfl_xor(p, 4, 64);
        if ((tid & 7) == 0) DIAGs[st] = p;
    };

    // GEMM-wave roles (wid 0..3): out quadrant (ih,dh), A block (ih,jh)
    const int q = wid;
    const int ih = (q == 1 || q == 2) ? 1 : 0;
    const int jh = (q == 2) ? 1 : 0;
    const int dh = (q >= 2) ? 1 : 0;
    const int iA = lo + 32 * ih, jB = lo + 32 * jh, dC = lo + 32 * dh;
    const bool doG1 = (q < 3), doDiag = (q == 0 || q == 2);
    const int nksA = ih ? 4 : 2;                   // causal skip
    // state-wave roles (wid 4..7)
    const int dhs = (wid >> 1) & 1, shs = wid & 1;
    const int dS = lo + 32 * dhs, sS = lo + 32 * shs;
    const float tdL = pwh[64 * cS + sS];

    f32x16 x;
    if (wid >= 4) {
        const float* xin = Buf + ((size_t)bh * cSC + sc) * cS * cS;
#pragma unroll
        for (int r = 0; r < 16; ++r) {
            x[r] = xin[(size_t)sS * cS + crow(r, hi) + 32 * dhs];
            stEl(XTs[0], crow(r, hi) + 32 * dhs, sS, x[r]);
        }
    }
    gload(0); tileWrite(); gload(1);
    BARRIER();

    bf16x8 rwf[4], vsf[4];
    for (int c = 0; c < cNS; ++c) {
        const int t0 = c * cL;
        const unsigned short* XTcur = XTs[c & 1];
        if (wid < 4) {
#pragma unroll
            for (int ks = 0; ks < 4; ++ks)
                rwf[ks] = ldRowFrag(RWs, iA, ks * 16 + hi * 8);
            if (doG1) {
                f32x16 a1;
#pragma unroll
                for (int i = 0; i < 16; ++i) a1[i] = 0.f;
#pragma unroll
                for (int ks = 0; ks < 4; ++ks) {
                    bf16x8 kwf = ldRowFrag(KWs, jB, ks * 16 + hi * 8);
                    a1 = __builtin_amdgcn_mfma_f32_32x32x16_bf16(rwf[ks], kwf, a1, 0, 0, 0);
                }
                const float dg = doDiag ? DIAGs[jB] : 0.f;
#pragma unroll
                for (int r = 0; r < 16; ++r) {
                    const int row = crow(r, hi) + 32 * ih;
                    const float v_ = (jB < row) ? a1[r] : ((jB == row) ? dg : 0.f);
                    stEl(As, row, jB, v_);
                }
            }
#pragma unroll
            for (int ks = 0; ks < 4; ++ks)
                vsf[ks] = ldColFrag(VSs, ks * 16 + hi * 8, dC);
        } else {
            f32x16 w;
#pragma unroll
            for (int i = 0; i < 16; ++i) w[i] = 0.f;
#pragma unroll
            for (int ks = 0; ks < 4; ++ks) {
                bf16x8 vaf = ldColFrag(VSs, ks * 16 + hi * 8, dS);
                bf16x8 k2f = ldColFrag(KW2s, ks * 16 + hi * 8, sS);
                w = __builtin_amdgcn_mfma_f32_32x32x16_bf16(vaf, k2f, w, 0, 0, 0);
            }
#pragma unroll
            for (int i = 0; i < 16; ++i) x[i] = tdL * x[i] + w[i];
        }
        BARRIER();                         // tile-c reads done; A + diag ready
        if (c + 1 < cNS) tileWrite();      // write tiles c+1 (regs prefetched)
        if (c < cNS - 2) gload(c + 2);     // issue next prefetch
        if (wid < 4) {
            f32x16 a3;
#pragma unroll
            for (int i = 0; i < 16; ++i) a3[i] = 0.f;
#pragma unroll
            for (int ks = 0; ks < 4; ++ks) {
                if (ks < nksA) {
                    bf16x8 af = ldRowFrag(As, iA, ks * 16 + hi * 8);
                    a3 = __builtin_amdgcn_mfma_f32_32x32x16_bf16(af, vsf[ks], a3, 0, 0, 0);
                }
            }
#pragma unroll
            for (int ks = 0; ks < 4; ++ks) {
                bf16x8 xf = ldRowFrag(XTcur, dC, ks * 16 + hi * 8);
                a3 = __builtin_amdgcn_mfma_f32_32x32x16_bf16(rwf[ks], xf, a3, 0, 0, 0);
            }
#pragma unroll
            for (int r = 0; r < 16; ++r)
                ob[(size_t)(t0 + crow(r, hi) + 32 * ih) * cTS + dC] = a3[r];
        } else {
            if (c + 1 < cNS) {
#pragma unroll
                for (int r = 0; r < 16; ++r)
                    stEl(XTs[(c + 1) & 1], crow(r, hi) + 32 * dhs, sS, x[r]);
            }
        }
        BARRIER();                         // tiles c+1 + X_{c+1} visible
    }
    if (wid >= 4 && sc == cSC - 1) {
        float* o2 = Out + (size_t)cB * cT * cTS + (size_t)bh * cS * cS;
#pragma unroll
        for (int r = 0; r < 16; ++r)
            o2[(size_t)sS * cS + crow(r, hi) + 32 * dhs] = x[r] * 128.0f;
    }
}

extern "C" void kernel_launch(void* const* d_in, const int* in_sizes, int n_in,
                              void* d_out, int out_size, void* d_ws,
                              size_t ws_size, hipStream_t stream) {
    const float* K    = (const float*)d_in[0];
    const float* V    = (const float*)d_in[1];
    const float* R    = (const float*)d_in[2];
    const float* S2in = (const float*)d_in[3];
    const float* TF   = (const float*)d_in[4];
    const float* TD   = (const float*)d_in[5];
    float* OutP = (float*)d_out;
    float* pwt = (float*)d_ws;                 // [32][130][64] f32 ~1.06 MB
    float* Buf = (float*)d_ws + wsBuf;         // [128][4][64][64] f32 = 8.4 MB
    (void)in_sizes; (void)n_in; (void)ws_size; (void)out_size;

    rwkv5_tables<<<dim3(cH), dim3(64), 0, stream>>>(TD, pwt);
    rwkv5_pass1<<<dim3(cBH, cSC - 1), dim3(256), 0, stream>>>(K, V, pwt, Buf);
    rwkv5_pass2<<<dim3(cBH), dim3(256), 0, stream>>>(S2in, pwt, Buf);
    rwkv5_pass3<<<dim3(cBH * cSC), dim3(512), 0, stream>>>(K, V, R, TF, pwt,
                                                           Buf, OutP);
}

// Round 7
// 251.299 us; speedup vs baseline: 3.2694x; 1.7736x over previous
//
#include <hip/hip_runtime.h>

// RWKV-5 WKV via chunked linear attention + MFMA, LDS-staged bf16 tiles.
// B=4, T=4096, H=32, S=64. State scaled: X = s_raw*SCALE (X' = td*X + k (x) v').
// Subchunk L=64: out = [strictTril(RW@KW^T) + diag]@VS + RW@X0
//                X_L = td^64 * (X0 + KW^T@VS)        (KW2 == KW * td^64 fold)
//   RW[i][s]=r_i[s]*td^i, KW[j][s]=k_j[s]*td^-(j+1), diag_i = sum_s r_i tf k_i
// pass1: from-zero superchunk partials. pass2: propagate entry states.
// pass3: main compute; waves0-3 A-GEMM/out-GEMM, waves4-7 state chain.
// Key perf choices: #pragma unroll 1 (I$-resident body), KW2 tile folded away,
// VS stored transposed (b64 row-frags), powers via v_exp/v_log intrinsics.

namespace {
constexpr int cB = 4, cT = 4096, cH = 32, cS = 64;
constexpr int cTS = cH * cS;                 // 2048
constexpr float cScale = 1.0f / 128.0f;
constexpr int cSC = 8, cSCL = cT / cSC;      // 8 superchunks of 512
constexpr int cL = 64, cNS = cSCL / cL;      // 8 subchunks of 64
constexpr int cBH = cB * cH;                 // 128
}

typedef __bf16 bf16x8 __attribute__((ext_vector_type(8)));
typedef float  f32x16 __attribute__((ext_vector_type(16)));
typedef unsigned short u16x4 __attribute__((ext_vector_type(4)));
typedef unsigned short u16x8 __attribute__((ext_vector_type(8)));

#define BARRIER() asm volatile("s_waitcnt lgkmcnt(0)\n\ts_barrier" ::: "memory")

__device__ __forceinline__ float hw_log2(float x) {
    return __builtin_amdgcn_logf(x);          // v_log_f32: log2(x)
}
__device__ __forceinline__ float hw_exp2(float x) {
    return __builtin_amdgcn_exp2f(x);         // v_exp_f32: 2^x
}

__device__ __forceinline__ int swzb(int row, int byteInRow) {
    return row * 128 + (byteInRow ^ ((row & 15) << 3));   // bf16 tile, 128B rows
}
__device__ __forceinline__ int crow(int r, int hi) {
    return (r & 3) + 8 * (r >> 2) + 4 * hi;               // 32x32 C-layout row
}
__device__ __forceinline__ unsigned short bfb(float x) {
    return __builtin_bit_cast(unsigned short, (__bf16)x);
}
__device__ __forceinline__ bf16x8 ldRowFrag(const unsigned short* T, int row, int col) {
    const char* p = (const char*)T;
    u16x4 a = *(const u16x4*)(p + swzb(row, col * 2));
    u16x4 b = *(const u16x4*)(p + swzb(row, col * 2 + 8));
    u16x8 r = {a[0], a[1], a[2], a[3], b[0], b[1], b[2], b[3]};
    return __builtin_bit_cast(bf16x8, r);
}
__device__ __forceinline__ bf16x8 ldColFrag(const unsigned short* T, int row0, int col) {
    const char* p = (const char*)T;
    u16x8 r;
#pragma unroll
    for (int e = 0; e < 8; ++e)
        r[e] = *(const unsigned short*)(p + swzb(row0 + e, col * 2));
    return __builtin_bit_cast(bf16x8, r);
}
__device__ __forceinline__ void stRow8(unsigned short* T, int row, int col, u16x8 v) {
    char* p = (char*)T;
    u16x4 a = {v[0], v[1], v[2], v[3]}, b = {v[4], v[5], v[6], v[7]};
    *(u16x4*)(p + swzb(row, col * 2)) = a;
    *(u16x4*)(p + swzb(row, col * 2 + 8)) = b;
}
__device__ __forceinline__ void stEl(unsigned short* T, int row, int col, float x) {
    *(unsigned short*)((char*)T + swzb(row, col * 2)) = bfb(x);
}

// ---------------- pass1: from-zero superchunk partials (sc 0..6) ------------
__global__ __launch_bounds__(256)
void rwkv5_pass1(const float* __restrict__ K, const float* __restrict__ V,
                 const float* __restrict__ TD, float* __restrict__ Buf) {
    __shared__ alignas(16) unsigned short KWs[4096], VSTs[4096];
    const int bh = blockIdx.x, sc = blockIdx.y;
    const int b = bh >> 5, h = bh & 31;
    const int tid = threadIdx.x, wid = tid >> 6, l = tid & 63;
    const int lo = l & 31, hi = l >> 5;
    const int dhs = wid >> 1, shs = wid & 1;
    const int dS = lo + 32 * dhs, sS = lo + 32 * shs;
    const size_t tbase = ((size_t)b * cT + (size_t)sc * cSCL) * cTS + h * cS;
    const float *kb = K + tbase, *vb = V + tbase;

    // staging role: row st (timestep), 16 cols at c16
    const int st = tid >> 2, c16 = (tid & 3) * 16;
    float ipw[16];
#pragma unroll
    for (int e = 0; e < 16; ++e) {
        const float l2 = hw_log2(TD[h * cS + c16 + e]);
        ipw[e] = hw_exp2(-(float)(st + 1) * l2);     // td^-(st+1)
    }
    float tdL = TD[h * cS + sS];
#pragma unroll
    for (int i = 0; i < 6; ++i) tdL *= tdL;          // td^64

    float kx[16], vx[16];
    auto gload = [&](int cc) {
        const int c_ = (cc < cNS) ? cc : cNS - 1;
        const size_t off = ((size_t)(c_ * cL + st)) * cTS + c16;
#pragma unroll
        for (int i = 0; i < 4; ++i) {
            *(float4*)&kx[i * 4] = *(const float4*)(kb + off + i * 4);
            *(float4*)&vx[i * 4] = *(const float4*)(vb + off + i * 4);
        }
    };
    auto tileWrite = [&]() {
        u16x8 w;
#pragma unroll
        for (int hf = 0; hf < 2; ++hf) {
#pragma unroll
            for (int e = 0; e < 8; ++e) w[e] = bfb(kx[hf * 8 + e] * ipw[hf * 8 + e]);
            stRow8(KWs, st, c16 + hf * 8, w);
        }
#pragma unroll
        for (int e = 0; e < 16; ++e) stEl(VSTs, c16 + e, st, vx[e] * cScale);
    };

    f32x16 x;
#pragma unroll
    for (int i = 0; i < 16; ++i) x[i] = 0.f;

    gload(0); tileWrite(); gload(1);
    BARRIER();
#pragma unroll 1
    for (int c = 0; c < cNS; ++c) {
        f32x16 w;
#pragma unroll
        for (int i = 0; i < 16; ++i) w[i] = 0.f;
#pragma unroll
        for (int ks = 0; ks < 4; ++ks) {
            bf16x8 vaf = ldRowFrag(VSTs, dS, ks * 16 + hi * 8);
            bf16x8 k2f = ldColFrag(KWs, ks * 16 + hi * 8, sS);
            w = __builtin_amdgcn_mfma_f32_32x32x16_bf16(vaf, k2f, w, 0, 0, 0);
        }
#pragma unroll
        for (int i = 0; i < 16; ++i) x[i] = tdL * (x[i] + w[i]);
        BARRIER();
        if (c + 1 < cNS) tileWrite();
        if (c < cNS - 2) gload(c + 2);
        BARRIER();
    }
    float* xp = Buf + ((size_t)bh * cSC + sc) * cS * cS;
#pragma unroll
    for (int r = 0; r < 16; ++r)
        xp[(size_t)sS * cS + crow(r, hi) + 32 * dhs] = x[r];
}

// ---------------- pass2: propagate entry states (in place) ------------------
__global__ __launch_bounds__(256)
void rwkv5_pass2(const float* __restrict__ S2in, const float* __restrict__ TD,
                 float* __restrict__ Buf) {
    const int bh = blockIdx.x, h = bh & 31;
    const int t = threadIdx.x, s = t >> 2, db = (t & 3) * 16;
    float d = TD[h * cS + s];
#pragma unroll
    for (int i = 0; i < 9; ++i) d *= d;               // td^512
    float4 x[4];
    const float* s0 = S2in + ((size_t)bh * cS + s) * cS + db;
#pragma unroll
    for (int i = 0; i < 4; ++i) {
        x[i] = *(const float4*)(s0 + i * 4);
        x[i].x *= cScale; x[i].y *= cScale; x[i].z *= cScale; x[i].w *= cScale;
    }
    for (int sc = 0; sc < cSC; ++sc) {
        float* base = Buf + (((size_t)bh * cSC + sc) * cS + s) * cS + db;
        float4 pr[4];
        if (sc < cSC - 1) {
#pragma unroll
            for (int i = 0; i < 4; ++i) pr[i] = *(const float4*)(base + i * 4);
        }
#pragma unroll
        for (int i = 0; i < 4; ++i) *(float4*)(base + i * 4) = x[i];
        if (sc < cSC - 1) {
#pragma unroll
            for (int i = 0; i < 4; ++i) {
                x[i].x = fmaf(d, x[i].x, pr[i].x);
                x[i].y = fmaf(d, x[i].y, pr[i].y);
                x[i].z = fmaf(d, x[i].z, pr[i].z);
                x[i].w = fmaf(d, x[i].w, pr[i].w);
            }
        }
    }
}

// ---------------- pass3: main compute ----------------------------------------
__global__ __launch_bounds__(512)
void rwkv5_pass3(const float* __restrict__ K, const float* __restrict__ V,
                 const float* __restrict__ R, const float* __restrict__ TF,
                 const float* __restrict__ TD, const float* __restrict__ Buf,
                 float* __restrict__ Out) {
    __shared__ alignas(16) unsigned short RWs[4096], KWs[4096], VSTs[4096],
                                          As[4096], XTs[2][4096];
    __shared__ float DIAGs[64];
    const int u = blockIdx.x, bh = u >> 3, sc = u & 7;
    const int b = bh >> 5, h = bh & 31;
    const int tid = threadIdx.x, wid = tid >> 6, l = tid & 63;
    const int lo = l & 31, hi = l >> 5;
    const size_t tbase = ((size_t)b * cT + (size_t)sc * cSCL) * cTS + h * cS;
    const float *kb = K + tbase, *vb = V + tbase, *rb = R + tbase;
    float* ob = Out + tbase;

    // staging role: row st (timestep), 8 cols at sc8
    const int st = tid >> 3, sc8 = (tid & 7) * 8;
    float pwA[8], ipwB[8], tfv[8];
#pragma unroll
    for (int e = 0; e < 8; ++e) {
        const float l2 = hw_log2(TD[h * cS + sc8 + e]);
        pwA[e]  = hw_exp2((float)st * l2);            // td^st
        ipwB[e] = hw_exp2(-(float)(st + 1) * l2);     // td^-(st+1)
        tfv[e]  = TF[h * cS + sc8 + e];
    }
    float kx[8], vx[8], rx[8];
    auto gload = [&](int cc) {
        const int c_ = (cc < cNS) ? cc : cNS - 1;
        const size_t off = ((size_t)(c_ * cL + st)) * cTS + sc8;
        *(float4*)&kx[0] = *(const float4*)(kb + off);
        *(float4*)&kx[4] = *(const float4*)(kb + off + 4);
        *(float4*)&vx[0] = *(const float4*)(vb + off);
        *(float4*)&vx[4] = *(const float4*)(vb + off + 4);
        *(float4*)&rx[0] = *(const float4*)(rb + off);
        *(float4*)&rx[4] = *(const float4*)(rb + off + 4);
    };
    auto tileWrite = [&]() {
        u16x8 w;
#pragma unroll
        for (int e = 0; e < 8; ++e) w[e] = bfb(rx[e] * pwA[e]);
        stRow8(RWs, st, sc8, w);
#pragma unroll
        for (int e = 0; e < 8; ++e) w[e] = bfb(kx[e] * ipwB[e]);
        stRow8(KWs, st, sc8, w);
#pragma unroll
        for (int e = 0; e < 8; ++e) stEl(VSTs, sc8 + e, st, vx[e] * cScale);
        float p = 0.f;
#pragma unroll
        for (int e = 0; e < 8; ++e) p = fmaf(rx[e] * tfv[e], kx[e], p);
        p += __shfl_xor(p, 1, 64);
        p += __shfl_xor(p, 2, 64);
        p += __shfl_xor(p, 4, 64);
        if ((tid & 7) == 0) DIAGs[st] = p;
    };

    // GEMM-wave roles (wid 0..3)
    const int q = wid;
    const int ih = (q == 1 || q == 2) ? 1 : 0;
    const int jh = (q == 2) ? 1 : 0;
    const int dh = (q >= 2) ? 1 : 0;
    const int iA = lo + 32 * ih, jB = lo + 32 * jh, dC = lo + 32 * dh;
    const bool doG1 = (q < 3), doDiag = (q == 0 || q == 2);
    const int nksA = ih ? 4 : 2;                      // causal skip
    // state-wave roles (wid 4..7)
    const int dhs = (wid >> 1) & 1, shs = wid & 1;
    const int dS = lo + 32 * dhs, sS = lo + 32 * shs;
    float tdL = TD[h * cS + sS];
#pragma unroll
    for (int i = 0; i < 6; ++i) tdL *= tdL;           // td^64

    f32x16 x;
    if (wid >= 4) {
        const float* xin = Buf + ((size_t)bh * cSC + sc) * cS * cS;
#pragma unroll
        for (int r = 0; r < 16; ++r) {
            x[r] = xin[(size_t)sS * cS + crow(r, hi) + 32 * dhs];
            stEl(XTs[0], crow(r, hi) + 32 * dhs, sS, x[r]);
        }
    }
    gload(0); tileWrite(); gload(1);
    BARRIER();

    const unsigned short* xt_rd = XTs[0];
    unsigned short*       xt_wr = XTs[1];
    bf16x8 rwf[4], vsf[4];
#pragma unroll 1
    for (int c = 0; c < cNS; ++c) {
        const int t0 = c * cL;
        if (wid < 4) {
            // ---- phase A: read tiles c, build A ----
#pragma unroll
            for (int ks = 0; ks < 4; ++ks)
                rwf[ks] = ldRowFrag(RWs, iA, ks * 16 + hi * 8);
            if (doG1) {
                f32x16 a1;
#pragma unroll
                for (int i = 0; i < 16; ++i) a1[i] = 0.f;
#pragma unroll
                for (int ks = 0; ks < 4; ++ks) {
                    bf16x8 kwf = ldRowFrag(KWs, jB, ks * 16 + hi * 8);
                    a1 = __builtin_amdgcn_mfma_f32_32x32x16_bf16(rwf[ks], kwf, a1, 0, 0, 0);
                }
                const float dg = doDiag ? DIAGs[jB] : 0.f;
#pragma unroll
                for (int r = 0; r < 16; ++r) {
                    const int row = crow(r, hi) + 32 * ih;
                    const float v_ = (jB < row) ? a1[r] : ((jB == row) ? dg : 0.f);
                    stEl(As, row, jB, v_);
                }
            }
#pragma unroll
            for (int ks = 0; ks < 4; ++ks)
                vsf[ks] = ldRowFrag(VSTs, dC, ks * 16 + hi * 8);
        } else {
            // ---- phase A: state chain ----
            f32x16 w;
#pragma unroll
            for (int i = 0; i < 16; ++i) w[i] = 0.f;
#pragma unroll
            for (int ks = 0; ks < 4; ++ks) {
                bf16x8 vaf = ldRowFrag(VSTs, dS, ks * 16 + hi * 8);
                bf16x8 k2f = ldColFrag(KWs, ks * 16 + hi * 8, sS);
                w = __builtin_amdgcn_mfma_f32_32x32x16_bf16(vaf, k2f, w, 0, 0, 0);
            }
#pragma unroll
            for (int i = 0; i < 16; ++i) x[i] = tdL * (x[i] + w[i]);
        }
        BARRIER();                         // tile-c reads done; A + diag ready
        if (c + 1 < cNS) tileWrite();      // write tiles c+1 (regs prefetched)
        if (c < cNS - 2) gload(c + 2);     // issue next prefetch
        if (wid < 4) {
            // ---- phase B: out = A@VS + RW@X ----
            f32x16 a3;
#pragma unroll
            for (int i = 0; i < 16; ++i) a3[i] = 0.f;
#pragma unroll
            for (int ks = 0; ks < 4; ++ks) {
                if (ks < nksA) {
                    bf16x8 af = ldRowFrag(As, iA, ks * 16 + hi * 8);
                    a3 = __builtin_amdgcn_mfma_f32_32x32x16_bf16(af, vsf[ks], a3, 0, 0, 0);
                }
            }
#pragma unroll
            for (int ks = 0; ks < 4; ++ks) {
                bf16x8 xf = ldRowFrag(xt_rd, dC, ks * 16 + hi * 8);
                a3 = __builtin_amdgcn_mfma_f32_32x32x16_bf16(rwf[ks], xf, a3, 0, 0, 0);
            }
#pragma unroll
            for (int r = 0; r < 16; ++r)
                ob[(size_t)(t0 + crow(r, hi) + 32 * ih) * cTS + dC] = a3[r];
        } else {
            if (c + 1 < cNS) {
#pragma unroll
                for (int r = 0; r < 16; ++r)
                    stEl(xt_wr, crow(r, hi) + 32 * dhs, sS, x[r]);
            }
        }
        BARRIER();                         // tiles c+1 + X_{c+1} visible
        const unsigned short* tmp = xt_rd;
        xt_rd = xt_wr;
        xt_wr = (unsigned short*)tmp;
    }
    if (wid >= 4 && sc == cSC - 1) {
        float* o2 = Out + (size_t)cB * cT * cTS + (size_t)bh * cS * cS;
#pragma unroll
        for (int r = 0; r < 16; ++r)
            o2[(size_t)sS * cS + crow(r, hi) + 32 * dhs] = x[r] * 128.0f;
    }
}

extern "C" void kernel_launch(void* const* d_in, const int* in_sizes, int n_in,
                              void* d_out, int out_size, void* d_ws,
                              size_t ws_size, hipStream_t stream) {
    const float* K    = (const float*)d_in[0];
    const float* V    = (const float*)d_in[1];
    const float* R    = (const float*)d_in[2];
    const float* S2in = (const float*)d_in[3];
    const float* TF   = (const float*)d_in[4];
    const float* TD   = (const float*)d_in[5];
    float* OutP = (float*)d_out;
    float* Buf  = (float*)d_ws;            // [128][8][64][64] f32 = 16.8 MB
    (void)in_sizes; (void)n_in; (void)ws_size; (void)out_size;

    rwkv5_pass1<<<dim3(cBH, cSC - 1), dim3(256), 0, stream>>>(K, V, TD, Buf);
    rwkv5_pass2<<<dim3(cBH), dim3(256), 0, stream>>>(S2in, TD, Buf);
    rwkv5_pass3<<<dim3(cBH * cSC), dim3(512), 0, stream>>>(K, V, R, TF, TD,
                                                           Buf, OutP);
}